// Round 8
// baseline (146.721 us; speedup 1.0000x reference)
//
#include <hip/hip_runtime.h>
#include <math.h>

#define T_IN 2048
#define TP   2051   // T+3 conv output length
#define F    256
#define H    384
#define BK   16     // k2 K-tile
#define BT3  48     // k2 t-tile
#define NT3  43     // ceil(TP/48) t-tiles in k2
#define NCS  257    // 8-t chunks (scan length)
#define NC3  257    // k3 chunks of 8

__device__ __forceinline__ float logsig(float z) {
    return (z >= 0.0f) ? -log1pf(__expf(-z)) : z - log1pf(__expf(z));
}

union F4 { float4 v; float f[4]; };

// ---------- D1: conv (blocks 0..512) + q/o GEMV (513..608) + zero (609) ----------
// qo path: xp[TP-1, f] = cb + cw[0]*x[2047, f] exactly (taps t>=2048 are out of
// range), so it needs no conv output -> safe to fuse in the same dispatch.
__global__ __launch_bounds__(256) void k1_front(const float* __restrict__ x,
        const float* __restrict__ cw, const float* __restrict__ cb,
        const float* __restrict__ Wq, const float* __restrict__ bq,
        const float* __restrict__ Wo, const float* __restrict__ bo,
        float* __restrict__ xp, float* __restrict__ q, float* __restrict__ o,
        float* __restrict__ zf) {
    int bid = blockIdx.x;
    int tid = threadIdx.x;
    if (bid < 513) {
        int t = bid * 4 + (tid >> 6);
        int f4 = tid & 63;
        if (t >= TP) return;
        float w[4] = {cw[0], cw[1], cw[2], cw[3]};
        float b = cb[0];
        float4 acc = {b, b, b, b};
        int i0 = t - 3;
        const float4* x4 = (const float4*)x;
        #pragma unroll
        for (int j = 0; j < 4; ++j) {
            int tt = i0 + j;
            if (tt >= 0 && tt < T_IN) {
                float4 xv = x4[tt * 64 + f4];
                acc.x = fmaf(w[j], xv.x, acc.x);
                acc.y = fmaf(w[j], xv.y, acc.y);
                acc.z = fmaf(w[j], xv.z, acc.z);
                acc.w = fmaf(w[j], xv.w, acc.w);
            }
        }
        ((float4*)xp)[t * 64 + f4] = acc;
    } else if (bid < 609) {
        int lane = tid & 63;
        int row = (bid - 513) * 4 + (tid >> 6);
        float w0 = cw[0], b = cb[0];
        float4 xr = ((const float4*)x)[2047 * 64 + lane];
        float4 xv;
        xv.x = fmaf(w0, xr.x, b);
        xv.y = fmaf(w0, xr.y, b);
        xv.z = fmaf(w0, xr.z, b);
        xv.w = fmaf(w0, xr.w, b);
        float4 q4 = *(const float4*)&Wq[row * 256 + lane * 4];
        float4 o4 = *(const float4*)&Wo[row * 256 + lane * 4];
        float aq = fmaf(xv.x, q4.x, fmaf(xv.y, q4.y, fmaf(xv.z, q4.z, xv.w * q4.w)));
        float ao = fmaf(xv.x, o4.x, fmaf(xv.y, o4.y, fmaf(xv.z, o4.z, xv.w * o4.w)));
        #pragma unroll
        for (int off = 32; off; off >>= 1) {
            aq += __shfl_down(aq, off, 64);
            ao += __shfl_down(ao, off, 64);
        }
        if (lane == 0) {
            q[row] = aq + bq[row];
            o[row] = 1.0f / (1.0f + __expf(-(ao + bo[row])));
        }
    } else {
        // zero zf (256) + Gf (at 256) + pad
        for (int i = tid; i < 272; i += 256) zf[i] = 0.0f;
    }
}

// ---------- D2: 48t x 64b x 1 matrix, 192 thr, 4t x 4b register tile ----------
// grid (43, 6, 3) = 774 blocks = 3.02/CU (balanced makespan).
// Per thread per kk: 1 ds_read_b128 (W float4) + amortized a-reads = 16 FMA
// against 32B LDS -> 0.125 LDS-instr/FMA (2x better than the 4t x 2b version;
// R2/R3 both ~40us and LDS-issue-bound). a-reads: 4-address broadcast; W-reads:
// 4-way ty-broadcast, row stride 68 floats (272B, 16B-aligned, <=2 lanes/bank).
__global__ __launch_bounds__(192) void k2_proj(
    const float* __restrict__ xp,
    const float* __restrict__ Wk, const float* __restrict__ bk,
    const float* __restrict__ Wi, const float* __restrict__ bi,
    const float* __restrict__ Wf, const float* __restrict__ bf,
    float* __restrict__ zk, float* __restrict__ ai, float* __restrict__ lf,
    float* __restrict__ cs) {
    __shared__ float alds[2][BT3][20];   // xp tile [t][k], pad 20 (16B-aligned rows)
    __shared__ float wlds[2][BK][68];    // W^T [k][b], pad 68 (16B-aligned rows)
    __shared__ float csred[12][68];      // per-ty-group lf sums [tgroup][b]
    int tid = threadIdx.x;
    int mz = blockIdx.z;
    const float* __restrict__ W    = (mz == 0) ? Wk : (mz == 1) ? Wi : Wf;
    const float* __restrict__ bias = (mz == 0) ? bk : (mz == 1) ? bi : bf;
    int t0 = blockIdx.x * BT3, b0 = blockIdx.y * 64;
    int tx = tid & 15, ty = tid >> 4;    // tx: b-quad (4b), ty: t-quad (4t)
    float4 acc[4];
    #pragma unroll
    for (int u = 0; u < 4; ++u) { acc[u].x = 0.f; acc[u].y = 0.f; acc[u].z = 0.f; acc[u].w = 0.f; }

    int srow = tid >> 2;          // 0..47 (staging row)
    int sk4 = (tid & 3) * 4;      // k quad
    int grow = (b0 + srow) * 256 + sk4;
    int grow2 = (b0 + 48 + srow) * 256 + sk4;   // W rows 48..63 (tid<64 only)
    int arow = (t0 + srow) * 256 + sk4;
    bool aval = (t0 + srow) < TP;

    float4 aw = {0.f, 0.f, 0.f, 0.f};
    float4 ww, ww2;
    // prologue: load tile 0
    if (aval) aw = *(const float4*)&xp[arow];
    ww = *(const float4*)&W[grow];
    if (tid < 64) ww2 = *(const float4*)&W[grow2];

    for (int i = 0; i < 16; ++i) {
        int buf = i & 1;
        *(float4*)&alds[buf][srow][sk4] = aw;
        {
            F4 wu; wu.v = ww;
            #pragma unroll
            for (int j = 0; j < 4; ++j)
                wlds[buf][sk4 + j][srow] = wu.f[j];
            if (tid < 64) {
                F4 w2u; w2u.v = ww2;
                #pragma unroll
                for (int j = 0; j < 4; ++j)
                    wlds[buf][sk4 + j][48 + srow] = w2u.f[j];
            }
        }
        __syncthreads();
        if (i < 15) {
            int k0 = (i + 1) * BK;
            if (aval) aw = *(const float4*)&xp[arow + k0];
            ww = *(const float4*)&W[grow + k0];
            if (tid < 64) ww2 = *(const float4*)&W[grow2 + k0];
        }
        #pragma unroll
        for (int g = 0; g < 4; ++g) {
            F4 av0, av1, av2, av3;
            av0.v = *(const float4*)&alds[buf][4 * ty + 0][4 * g];
            av1.v = *(const float4*)&alds[buf][4 * ty + 1][4 * g];
            av2.v = *(const float4*)&alds[buf][4 * ty + 2][4 * g];
            av3.v = *(const float4*)&alds[buf][4 * ty + 3][4 * g];
            #pragma unroll
            for (int j = 0; j < 4; ++j) {
                float4 wv = *(const float4*)&wlds[buf][4 * g + j][4 * tx];
                acc[0].x = fmaf(av0.f[j], wv.x, acc[0].x);
                acc[0].y = fmaf(av0.f[j], wv.y, acc[0].y);
                acc[0].z = fmaf(av0.f[j], wv.z, acc[0].z);
                acc[0].w = fmaf(av0.f[j], wv.w, acc[0].w);
                acc[1].x = fmaf(av1.f[j], wv.x, acc[1].x);
                acc[1].y = fmaf(av1.f[j], wv.y, acc[1].y);
                acc[1].z = fmaf(av1.f[j], wv.z, acc[1].z);
                acc[1].w = fmaf(av1.f[j], wv.w, acc[1].w);
                acc[2].x = fmaf(av2.f[j], wv.x, acc[2].x);
                acc[2].y = fmaf(av2.f[j], wv.y, acc[2].y);
                acc[2].z = fmaf(av2.f[j], wv.z, acc[2].z);
                acc[2].w = fmaf(av2.f[j], wv.w, acc[2].w);
                acc[3].x = fmaf(av3.f[j], wv.x, acc[3].x);
                acc[3].y = fmaf(av3.f[j], wv.y, acc[3].y);
                acc[3].z = fmaf(av3.f[j], wv.z, acc[3].z);
                acc[3].w = fmaf(av3.f[j], wv.w, acc[3].w);
            }
        }
    }
    // epilogue: 4 t-rows x 4 b-cols per thread, one matrix
    int bA = b0 + 4 * tx;
    float4 b4 = *(const float4*)&bias[bA];
    if (mz == 0) {
        const float sc = 0.05103103630798287f;  // 1/sqrt(384)
        #pragma unroll
        for (int u = 0; u < 4; ++u) {
            int t = t0 + 4 * ty + u;
            if (t < TP) {
                float4 v;
                v.x = (acc[u].x + b4.x) * sc; v.y = (acc[u].y + b4.y) * sc;
                v.z = (acc[u].z + b4.z) * sc; v.w = (acc[u].w + b4.w) * sc;
                *(float4*)&zk[t * H + bA] = v;
            }
        }
    } else if (mz == 1) {
        #pragma unroll
        for (int u = 0; u < 4; ++u) {
            int t = t0 + 4 * ty + u;
            if (t < TP) {
                float4 v;
                v.x = acc[u].x + b4.x; v.y = acc[u].y + b4.y;
                v.z = acc[u].z + b4.z; v.w = acc[u].w + b4.w;
                *(float4*)&ai[t * H + bA] = v;
            }
        }
    } else {
        float4 lsum = {0.f, 0.f, 0.f, 0.f};
        #pragma unroll
        for (int u = 0; u < 4; ++u) {
            int t = t0 + 4 * ty + u;
            if (t < TP) {
                float4 l4;
                l4.x = logsig(acc[u].x + b4.x);
                l4.y = logsig(acc[u].y + b4.y);
                l4.z = logsig(acc[u].z + b4.z);
                l4.w = logsig(acc[u].w + b4.w);
                *(float4*)&lf[t * H + bA] = l4;
                lsum.x += l4.x; lsum.y += l4.y; lsum.z += l4.z; lsum.w += l4.w;
            }
        }
        // per-8t chunk sums: ty pair (2c, 2c+1) covers chunk c (48t = 6 chunks)
        *(float4*)&csred[ty][4 * tx] = lsum;
        __syncthreads();
        for (int cc = tid; cc < 384; cc += 192) {
            int cl = cc >> 6;        // 0..5 local chunk
            int bb = cc & 63;
            int c = blockIdx.x * 6 + cl;
            if (c < NCS)
                cs[c * H + b0 + bb] = csred[2 * cl][bb] + csred[2 * cl + 1][bb];
        }
    }
}

// ---------- D3: reverse exclusive scan over 257 chunk sums, grid 6x64 ----------
__global__ __launch_bounds__(64) void k3b_scan(const float* __restrict__ cs,
                                               float* __restrict__ co) {
    int b = blockIdx.x * 64 + threadIdx.x;
    float L = 0.0f;
    #pragma unroll 16
    for (int c = NCS - 1; c >= 0; --c) {
        co[c * H + b] = L;
        L += cs[c * H + b];
    }
}

// ---------- D4: fused w -> g -> atomic (z, G). grid NC3 x 384, chunk 8 t ----------
// No fence/ticket epilogue: R5/R6 showed device-scope __threadfence storms cost
// ~80-100us (VALU 0.7%, HBM 0.8%, dur 105-127us). Dispatch boundary is free.
__global__ __launch_bounds__(384) void k3_fused(
    const float* __restrict__ ai, const float* __restrict__ lf,
    const float* __restrict__ zk, const float* __restrict__ co,
    const float* __restrict__ q, const float* __restrict__ xp,
    float* __restrict__ zf, float* __restrict__ Gf) {
    __shared__ float zred[6][256];
    __shared__ float gred[6];
    int tid = threadIdx.x;
    int w = tid >> 6, lane = tid & 63;
    int c = blockIdx.x, ts = c * 8;
    float co0 = co[c * H + tid];
    float qb = q[tid];
    float aiv[8], lfv[8], zkv[8];
    float4 xv[8];
    if (ts + 8 <= TP) {
        #pragma unroll
        for (int u = 0; u < 8; ++u) {
            int idx = (ts + u) * H + tid;
            aiv[u] = ai[idx]; lfv[u] = lf[idx]; zkv[u] = zk[idx];
            xv[u] = *(const float4*)&xp[(ts + u) * 256 + lane * 4];
        }
    } else {
        #pragma unroll
        for (int u = 0; u < 8; ++u) {
            if (ts + u < TP) {
                int idx = (ts + u) * H + tid;
                aiv[u] = ai[idx]; lfv[u] = lf[idx]; zkv[u] = zk[idx];
                xv[u] = *(const float4*)&xp[(ts + u) * 256 + lane * 4];
            } else {
                aiv[u] = -1e30f; lfv[u] = 0.f; zkv[u] = 0.f;
                xv[u].x = xv[u].y = xv[u].z = xv[u].w = 0.f;
            }
        }
    }
    float S = 0.f, gsum = 0.f;
    float z0 = 0.f, z1 = 0.f, z2 = 0.f, z3 = 0.f;
    #pragma unroll
    for (int u = 7; u >= 0; --u) {
        float wv = __expf(aiv[u] + co0 + S) * zkv[u] * qb;
        S += lfv[u];
        float s = wv;
        s += __shfl_xor(s, 1, 64);
        s += __shfl_xor(s, 2, 64);
        s += __shfl_xor(s, 4, 64);
        s += __shfl_xor(s, 8, 64);
        s += __shfl_xor(s, 16, 64);
        s += __shfl_xor(s, 32, 64);
        gsum += s;
        z0 = fmaf(s, xv[u].x, z0);
        z1 = fmaf(s, xv[u].y, z1);
        z2 = fmaf(s, xv[u].z, z2);
        z3 = fmaf(s, xv[u].w, z3);
    }
    zred[w][lane * 4 + 0] = z0;
    zred[w][lane * 4 + 1] = z1;
    zred[w][lane * 4 + 2] = z2;
    zred[w][lane * 4 + 3] = z3;
    if (lane == 0) gred[w] = gsum;
    __syncthreads();
    if (tid < 256) {
        float s = zred[0][tid] + zred[1][tid] + zred[2][tid]
                + zred[3][tid] + zred[4][tid] + zred[5][tid];
        atomicAdd(&zf[tid], s);
    }
    if (tid == 0)
        atomicAdd(Gf, gred[0] + gred[1] + gred[2] + gred[3] + gred[4] + gred[5]);
}

// ---------- D5: wave-per-row GEMV finalize, grid 96 ----------
__global__ __launch_bounds__(256) void k6_out(const float* __restrict__ zf,
        const float* __restrict__ Gf,
        const float* __restrict__ Wv, const float* __restrict__ bv,
        const float* __restrict__ o, float* __restrict__ out) {
    int tid = threadIdx.x;
    int lane = tid & 63;
    int row = blockIdx.x * 4 + (tid >> 6);
    float Gv = Gf[0];
    float4 zv = *(const float4*)&zf[lane * 4];
    float4 wv = *(const float4*)&Wv[row * 256 + lane * 4];
    float acc = fmaf(zv.x, wv.x, fmaf(zv.y, wv.y, fmaf(zv.z, wv.z, zv.w * wv.w)));
    #pragma unroll
    for (int off = 32; off; off >>= 1) acc += __shfl_down(acc, off, 64);
    if (lane == 0)
        out[row] = o[row] * (acc + bv[row] * Gv) / fmaxf(fabsf(Gv), 1.0f);
}

extern "C" void kernel_launch(void* const* d_in, const int* in_sizes, int n_in,
                              void* d_out, int out_size, void* d_ws, size_t ws_size,
                              hipStream_t stream) {
    const float* x  = (const float*)d_in[0];
    const float* Wq = (const float*)d_in[1];  const float* bq = (const float*)d_in[2];
    const float* Wk = (const float*)d_in[3];  const float* bk = (const float*)d_in[4];
    const float* Wv = (const float*)d_in[5];  const float* bv = (const float*)d_in[6];
    const float* Wi = (const float*)d_in[7];  const float* bi = (const float*)d_in[8];
    const float* Wf = (const float*)d_in[9];  const float* bf = (const float*)d_in[10];
    const float* Wo = (const float*)d_in[11]; const float* bo = (const float*)d_in[12];
    const float* cw = (const float*)d_in[13]; const float* cb = (const float*)d_in[14];
    float* out = (float*)d_out;

    float* ws = (float*)d_ws;
    float* xp  = ws;                       // TP*F   = 525056
    float* zk  = xp  + TP * F;             // TP*H   = 787584
    float* ai  = zk  + TP * H;             // TP*H
    float* lf  = ai  + TP * H;             // TP*H
    float* cs  = lf  + TP * H;             // NCS*H  = 98688
    float* co  = cs  + NCS * H;            // NCS*H
    float* qv  = co  + NCS * H;            // H
    float* ov  = qv  + H;                  // H
    float* zf  = ov  + H;                  // F (z accumulator)
    float* Gf  = zf  + F;                  // 1 (zf+256)

    k1_front<<<610, 256, 0, stream>>>(x, cw, cb, Wq, bq, Wo, bo, xp, qv, ov, zf);
    k2_proj<<<dim3(NT3, 6, 3), 192, 0, stream>>>(xp, Wk, bk, Wi, bi, Wf, bf, zk, ai, lf, cs);
    k3b_scan<<<6, 64, 0, stream>>>(cs, co);
    k3_fused<<<NC3, 384, 0, stream>>>(ai, lf, zk, co, qv, xp, zf, Gf);
    k6_out<<<96, 256, 0, stream>>>(zf, Gf, Wv, bv, ov, out);
}